// Round 2
// baseline (1030.914 us; speedup 1.0000x reference)
//
#include <hip/hip_runtime.h>

#define NN 50000
#define NE 800000

// ws element offsets (4-byte units), 64-element aligned; O_EINFO 8B-aligned
#define O_DEGIN   0
#define O_DEGOUT  50048
#define O_ROWPTR  100096
#define O_CURSOR  150208
#define O_EINFO   200256
#define O_PF      1800256
#define O_PD      8200256
#define O_ZN      14600256
#define O_LOOPB   14650304
#define O_HPRE    16250304
#define O_H1      17850304
// total = 19450304 elems = ~77.8 MB

// ---------------- setup kernels ----------------

__global__ __launch_bounds__(256) void k_deg(const int* __restrict__ src,
                                             const int* __restrict__ dst,
                                             int* degin, int* degout) {
    int e = blockIdx.x * 256 + threadIdx.x;
    if (e < NE) {
        atomicAdd(&degin[dst[e]], 1);
        atomicAdd(&degout[src[e]], 1);
    }
}

__global__ __launch_bounds__(1024) void k_scan(const int* __restrict__ degin,
                                               int* rowptr, int* cursor) {
    __shared__ int sb[1024];
    int t = threadIdx.x;
    int carry = 0;
    for (int b0 = 0; b0 < NN; b0 += 4096) {
        int i0 = b0 + t * 4;
        int v0 = 0, v1 = 0, v2 = 0, v3 = 0;
        if (i0 + 3 < NN) {
            v0 = degin[i0]; v1 = degin[i0 + 1]; v2 = degin[i0 + 2]; v3 = degin[i0 + 3];
        } else {
            if (i0     < NN) v0 = degin[i0];
            if (i0 + 1 < NN) v1 = degin[i0 + 1];
            if (i0 + 2 < NN) v2 = degin[i0 + 2];
            if (i0 + 3 < NN) v3 = degin[i0 + 3];
        }
        int s = v0 + v1 + v2 + v3;
        sb[t] = s;
        __syncthreads();
        for (int off = 1; off < 1024; off <<= 1) {
            int x = (t >= off) ? sb[t - off] : 0;
            __syncthreads();
            sb[t] += x;
            __syncthreads();
        }
        int excl = carry + sb[t] - s;
        int tot = sb[1023];
        if (i0     < NN) { rowptr[i0]     = excl; cursor[i0]     = excl; } excl += v0;
        if (i0 + 1 < NN) { rowptr[i0 + 1] = excl; cursor[i0 + 1] = excl; } excl += v1;
        if (i0 + 2 < NN) { rowptr[i0 + 2] = excl; cursor[i0 + 2] = excl; } excl += v2;
        if (i0 + 3 < NN) { rowptr[i0 + 3] = excl; cursor[i0 + 3] = excl; }
        carry += tot;
        __syncthreads();
    }
    if (t == 0) rowptr[NN] = carry;
}

__global__ __launch_bounds__(256) void k_scatter(const int* __restrict__ src,
                                                 const int* __restrict__ dst,
                                                 const int* __restrict__ eid,
                                                 int* cursor, int2* einfo) {
    int e = blockIdx.x * 256 + threadIdx.x;
    if (e >= NE) return;
    int slot = atomicAdd(&cursor[dst[e]], 1);
    einfo[slot] = make_int2(src[e] | (eid[e] << 20), e);
}

// ---------------- per-layer kernels ----------------

// One thread per node: Pf[r][n][:], Pd[r][n][:], zn[n], loopb[n][:]
__global__ __launch_bounds__(256) void k_nodeproj(const float* __restrict__ feat,
                                                  const float* __restrict__ nfeat,
                                                  const float* __restrict__ Wr,
                                                  const float* __restrict__ attw,
                                                  const float* __restrict__ lw,
                                                  const int* __restrict__ degout,
                                                  float* __restrict__ Pf,
                                                  float* __restrict__ Pd,
                                                  float* __restrict__ zn,
                                                  float* __restrict__ loopb) {
    int n = blockIdx.x * 256 + threadIdx.x;
    if (n >= NN) return;
    int dg = degout[n];
    float sc0 = rsqrtf((float)(dg > 1 ? dg : 1));
    const float* fin = feat + (size_t)n * 32;
    const float* nin = nfeat + (size_t)n * 32;
    float acc[32];

    for (int r = 0; r < 4; r++) {
        const float* W = Wr + (size_t)r * 96 * 32;  // rows 0:32 (feat part)
#pragma unroll
        for (int i = 0; i < 32; i++) acc[i] = 0.f;
        for (int k4 = 0; k4 < 32; k4 += 4) {
            float4 f4 = *(const float4*)&fin[k4];
            f4.x *= sc0; f4.y *= sc0; f4.z *= sc0; f4.w *= sc0;
            const float* Wk = W + k4 * 32;
#pragma unroll
            for (int i = 0; i < 32; i++) acc[i] += f4.x * Wk[i];
#pragma unroll
            for (int i = 0; i < 32; i++) acc[i] += f4.y * Wk[32 + i];
#pragma unroll
            for (int i = 0; i < 32; i++) acc[i] += f4.z * Wk[64 + i];
#pragma unroll
            for (int i = 0; i < 32; i++) acc[i] += f4.w * Wk[96 + i];
        }
        float* po = Pf + ((size_t)r * NN + n) * 32;
#pragma unroll
        for (int i = 0; i < 32; i += 4)
            *(float4*)&po[i] = make_float4(acc[i], acc[i + 1], acc[i + 2], acc[i + 3]);

        const float* W2 = W + 64 * 32;              // rows 64:96 (dst part)
#pragma unroll
        for (int i = 0; i < 32; i++) acc[i] = 0.f;
        for (int k4 = 0; k4 < 32; k4 += 4) {
            float4 f4 = *(const float4*)&nin[k4];
            const float* Wk = W2 + k4 * 32;
#pragma unroll
            for (int i = 0; i < 32; i++) acc[i] += f4.x * Wk[i];
#pragma unroll
            for (int i = 0; i < 32; i++) acc[i] += f4.y * Wk[32 + i];
#pragma unroll
            for (int i = 0; i < 32; i++) acc[i] += f4.z * Wk[64 + i];
#pragma unroll
            for (int i = 0; i < 32; i++) acc[i] += f4.w * Wk[96 + i];
        }
        float* qo = Pd + ((size_t)r * NN + n) * 32;
#pragma unroll
        for (int i = 0; i < 32; i += 4)
            *(float4*)&qo[i] = make_float4(acc[i], acc[i + 1], acc[i + 2], acc[i + 3]);
    }

    // loopb = node_feat @ loop_w
#pragma unroll
    for (int i = 0; i < 32; i++) acc[i] = 0.f;
    for (int k4 = 0; k4 < 32; k4 += 4) {
        float4 f4 = *(const float4*)&nin[k4];
        const float* Wk = lw + k4 * 32;
#pragma unroll
        for (int i = 0; i < 32; i++) acc[i] += f4.x * Wk[i];
#pragma unroll
        for (int i = 0; i < 32; i++) acc[i] += f4.y * Wk[32 + i];
#pragma unroll
        for (int i = 0; i < 32; i++) acc[i] += f4.z * Wk[64 + i];
#pragma unroll
        for (int i = 0; i < 32; i++) acc[i] += f4.w * Wk[96 + i];
    }
    float* lo = loopb + (size_t)n * 32;
#pragma unroll
    for (int i = 0; i < 32; i += 4)
        *(float4*)&lo[i] = make_float4(acc[i], acc[i + 1], acc[i + 2], acc[i + 3]);

    // zn = node_feat . attn_w[0:32]
    float z = 0.f;
    for (int k = 0; k < 32; k++) z += nin[k] * attw[k];
    zn[n] = z;
}

// Fused edge+aggregate: one 32-lane half-wave per dst node, lane = out column.
// Per edge: gather Pf[r][s][c], efeat[e][c] (coalesced 128B lines), GEMV via
// LDS weights + shfl-broadcast of ef, online softmax-weighted accumulation.
__global__ __launch_bounds__(256) void k_fagg(const int* __restrict__ rowptr,
                                              const int2* __restrict__ einfo,
                                              const float* __restrict__ efeat,
                                              const float* __restrict__ Wr,
                                              const float* __restrict__ attw,
                                              const float* __restrict__ Pf,
                                              const float* __restrict__ Pd,
                                              const float* __restrict__ zn,
                                              const float* __restrict__ loopb,
                                              const float* __restrict__ hbias,
                                              float* __restrict__ hpre) {
    __shared__ float sW[4 * 1024];   // W[r][k][c] = Wr[r][32+k][c]  (16 KB)
    __shared__ float sA[32];
    int tid = threadIdx.x;
    // stage edge-part weights: lds[r*1024 + q] = Wr[r*3072 + 1024 + q]
    for (int i = tid * 4; i < 4096; i += 1024) {
        int r = i >> 10, q = i & 1023;
        *(float4*)&sW[i] = *(const float4*)&Wr[r * 3072 + 1024 + q];
    }
    if (tid < 32) sA[tid] = attw[32 + tid];
    __syncthreads();

    int c = tid & 31;
    int n = blockIdx.x * 8 + (tid >> 5);
    if (n >= NN) return;

    int rp0 = rowptr[n];
    int deg = rowptr[n + 1] - rp0;
    // Pd for all 4 relations of this node (relation varies per edge)
    float pd0 = Pd[((size_t)0 * NN + n) * 32 + c];
    float pd1 = Pd[((size_t)1 * NN + n) * 32 + c];
    float pd2 = Pd[((size_t)2 * NN + n) * 32 + c];
    float pd3 = Pd[((size_t)3 * NN + n) * 32 + c];
    float znd = zn[n];
    float aw = sA[c];
    float num = 0.f, den = 0.f;

    for (int t = 0; t < deg; t++) {
        int2 me = einfo[rp0 + t];        // broadcast load (same addr per half)
        int s = me.x & 0xFFFFF;
        int r = me.x >> 20;
        float pf = Pf[((size_t)r * NN + s) * 32 + c];
        float ef = efeat[(size_t)me.y * 32 + c];
        const float* w = &sW[(r << 10) + c];
        float a0 = 0.f, a1 = 0.f, a2 = 0.f, a3 = 0.f;
#pragma unroll
        for (int k = 0; k < 32; k += 4) {
            a0 += __shfl(ef, k,     32) * w[k * 32];
            a1 += __shfl(ef, k + 1, 32) * w[(k + 1) * 32];
            a2 += __shfl(ef, k + 2, 32) * w[(k + 2) * 32];
            a3 += __shfl(ef, k + 3, 32) * w[(k + 3) * 32];
        }
        float pd = (r == 0) ? pd0 : (r == 1) ? pd1 : (r == 2) ? pd2 : pd3;
        float m = pf + pd + ((a0 + a1) + (a2 + a3));
        // z = zn[d] + m . attw[32:64]; reduce across the 32-lane half
        float zq = m * aw;
        zq += __shfl_xor(zq, 16, 32);
        zq += __shfl_xor(zq, 8, 32);
        zq += __shfl_xor(zq, 4, 32);
        zq += __shfl_xor(zq, 2, 32);
        zq += __shfl_xor(zq, 1, 32);
        float z = znd + zq;
        z = z > 0.f ? z : 0.01f * z;     // leaky_relu
        float ezv = __expf(z);           // softmax max-shift cancels
        num += ezv * m;
        den += ezv;
    }
    float h = (deg > 0) ? num / den : 0.f;
    h += loopb[(size_t)n * 32 + c];
    h *= rsqrtf((float)(deg > 1 ? deg : 1));
    h += hbias[c];
    hpre[(size_t)n * 32 + c] = h;
}

// One thread per node: AMRM + relu -> layer output
__global__ __launch_bounds__(256) void k_amrm(const float* __restrict__ hpre,
                                              const float* __restrict__ aW,
                                              const float* __restrict__ ab,
                                              const float* __restrict__ aa,
                                              float* __restrict__ out) {
    int n = blockIdx.x * 256 + threadIdx.x;
    if (n >= NN) return;
    const float* hp = hpre + (size_t)n * 32;

    float s[3];
#pragma unroll
    for (int l = 0; l < 3; l++) {
        float acc[32];
#pragma unroll
        for (int o = 0; o < 32; o++) acc[o] = ab[l * 32 + o];
        for (int h4 = 0; h4 < 32; h4 += 4) {
            float4 hv = *(const float4*)&hp[h4];
            const float* Wk = aW + ((size_t)l * 32 + h4) * 32;
#pragma unroll
            for (int o = 0; o < 32; o++) acc[o] += hv.x * Wk[o];
#pragma unroll
            for (int o = 0; o < 32; o++) acc[o] += hv.y * Wk[32 + o];
#pragma unroll
            for (int o = 0; o < 32; o++) acc[o] += hv.z * Wk[64 + o];
#pragma unroll
            for (int o = 0; o < 32; o++) acc[o] += hv.w * Wk[96 + o];
        }
        float sl = 0.f;
#pragma unroll
        for (int o = 0; o < 32; o++) {
            float lv = acc[o] > 0.f ? acc[o] : 0.f;
            sl += lv * aa[o];
        }
        s[l] = sl;
    }
    float mx = fmaxf(s[0], fmaxf(s[1], s[2]));
    float e0 = __expf(s[0] - mx), e1 = __expf(s[1] - mx), e2 = __expf(s[2] - mx);
    float inv = 1.f / (e0 + e1 + e2);
    float scl[3] = {e0 * inv, e1 * inv, e2 * inv};

    float outv[32];
#pragma unroll
    for (int o = 0; o < 32; o++) outv[o] = 0.f;
#pragma unroll
    for (int l = 0; l < 3; l++) {
        float acc[32];
#pragma unroll
        for (int o = 0; o < 32; o++) acc[o] = ab[l * 32 + o];
        for (int h4 = 0; h4 < 32; h4 += 4) {
            float4 hv = *(const float4*)&hp[h4];
            const float* Wk = aW + ((size_t)l * 32 + h4) * 32;
#pragma unroll
            for (int o = 0; o < 32; o++) acc[o] += hv.x * Wk[o];
#pragma unroll
            for (int o = 0; o < 32; o++) acc[o] += hv.y * Wk[32 + o];
#pragma unroll
            for (int o = 0; o < 32; o++) acc[o] += hv.z * Wk[64 + o];
#pragma unroll
            for (int o = 0; o < 32; o++) acc[o] += hv.w * Wk[96 + o];
        }
#pragma unroll
        for (int o = 0; o < 32; o++) {
            float lv = acc[o] > 0.f ? acc[o] : 0.f;
            outv[o] += scl[l] * lv;
        }
    }
    float* op = out + (size_t)n * 32;
#pragma unroll
    for (int o = 0; o < 32; o += 4) {
        float4 v = make_float4(fmaxf(outv[o], 0.f), fmaxf(outv[o + 1], 0.f),
                               fmaxf(outv[o + 2], 0.f), fmaxf(outv[o + 3], 0.f));
        *(float4*)&op[o] = v;
    }
}

// ---------------- host ----------------

static void launch_layer(const float* feat, const float* nf, const float* efeat,
                         const float* Wr, const float* attw, const float* lw,
                         const float* hb, const float* aW, const float* ab,
                         const float* aa, float* wsf, int* wsi, float* out,
                         hipStream_t stream) {
    k_nodeproj<<<196, 256, 0, stream>>>(feat, nf, Wr, attw, lw, wsi + O_DEGOUT,
                                        wsf + O_PF, wsf + O_PD, wsf + O_ZN, wsf + O_LOOPB);
    k_fagg<<<NN / 8, 256, 0, stream>>>(wsi + O_ROWPTR, (const int2*)(wsi + O_EINFO),
                                       efeat, Wr, attw, wsf + O_PF, wsf + O_PD,
                                       wsf + O_ZN, wsf + O_LOOPB, hb, wsf + O_HPRE);
    k_amrm<<<196, 256, 0, stream>>>(wsf + O_HPRE, aW, ab, aa, out);
}

extern "C" void kernel_launch(void* const* d_in, const int* in_sizes, int n_in,
                              void* d_out, int out_size, void* d_ws, size_t ws_size,
                              hipStream_t stream) {
    const float* x     = (const float*)d_in[0];
    const float* nfeat = (const float*)d_in[1];
    const float* efeat = (const float*)d_in[2];
    const int*   src   = (const int*)d_in[3];
    const int*   dst   = (const int*)d_in[4];
    const int*   eid   = (const int*)d_in[5];
    const float* Wr1   = (const float*)d_in[6];
    const float* attw1 = (const float*)d_in[7];
    const float* lw1   = (const float*)d_in[8];
    const float* hb1   = (const float*)d_in[9];
    const float* aW1   = (const float*)d_in[10];
    const float* ab1   = (const float*)d_in[11];
    const float* aa1   = (const float*)d_in[12];
    const float* Wr2   = (const float*)d_in[13];
    const float* attw2 = (const float*)d_in[14];
    const float* lw2   = (const float*)d_in[15];
    const float* hb2   = (const float*)d_in[16];
    const float* aW2   = (const float*)d_in[17];
    const float* ab2   = (const float*)d_in[18];
    const float* aa2   = (const float*)d_in[19];

    float* wsf = (float*)d_ws;
    int*   wsi = (int*)d_ws;
    float* out = (float*)d_out;

    // zero degree counters (degin + degout)
    hipMemsetAsync(d_ws, 0, (size_t)O_ROWPTR * 4, stream);

    k_deg<<<NE / 256, 256, 0, stream>>>(src, dst, wsi + O_DEGIN, wsi + O_DEGOUT);
    k_scan<<<1, 1024, 0, stream>>>(wsi + O_DEGIN, wsi + O_ROWPTR, wsi + O_CURSOR);
    k_scatter<<<NE / 256, 256, 0, stream>>>(src, dst, eid, wsi + O_CURSOR,
                                            (int2*)(wsi + O_EINFO));

    // layer 1: feat = x -> h1 (ws)
    launch_layer(x, nfeat, efeat, Wr1, attw1, lw1, hb1, aW1, ab1, aa1,
                 wsf, wsi, wsf + O_H1, stream);
    // layer 2: feat = h1 -> d_out
    launch_layer(wsf + O_H1, nfeat, efeat, Wr2, attw2, lw2, hb2, aW2, ab2, aa2,
                 wsf, wsi, out, stream);
}

// Round 3
// 889.375 us; speedup vs baseline: 1.1591x; 1.1591x over previous
//
#include <hip/hip_runtime.h>

#define NN 50000
#define NE 800000

// ws element offsets (4-byte units), 64-element aligned; O_EINFO 8B-aligned
#define O_DEGIN   0
#define O_DEGOUT  50048
#define O_ROWPTR  100096
#define O_CURSOR  150208
#define O_EINFO   200256
#define O_FEATN   1800256
#define O_ZF      3400256
#define O_ZNRD    3600320
#define O_PD      3800384
#define O_LOOPB   10200384
#define O_VV      11800384
#define O_HPRE    11800576
#define O_H1      13400576
// end 15000576 elems = ~60 MB

// ---------------- setup kernels ----------------

__global__ __launch_bounds__(256) void k_deg(const int* __restrict__ src,
                                             const int* __restrict__ dst,
                                             int* degin, int* degout) {
    int e = blockIdx.x * 256 + threadIdx.x;
    if (e < NE) {
        atomicAdd(&degin[dst[e]], 1);
        atomicAdd(&degout[src[e]], 1);
    }
}

// single-block scan, 16 elems/thread, 4 chunks of 16384
__global__ __launch_bounds__(1024) void k_scan(const int* __restrict__ degin,
                                               int* rowptr, int* cursor) {
    __shared__ int sb[1024];
    int t = threadIdx.x;
    int carry = 0;
    for (int ch = 0; ch < 4; ch++) {
        int base = ch * 16384 + t * 16;
        int v[16];
        int s = 0;
#pragma unroll
        for (int j = 0; j < 16; j++) {
            v[j] = (base + j < NN) ? degin[base + j] : 0;
            s += v[j];
        }
        sb[t] = s;
        __syncthreads();
        for (int off = 1; off < 1024; off <<= 1) {
            int x = (t >= off) ? sb[t - off] : 0;
            __syncthreads();
            sb[t] += x;
            __syncthreads();
        }
        int excl = carry + sb[t] - s;
        int tot = sb[1023];
#pragma unroll
        for (int j = 0; j < 16; j++) {
            if (base + j < NN) { rowptr[base + j] = excl; cursor[base + j] = excl; }
            excl += v[j];
        }
        carry += tot;
        __syncthreads();
    }
    if (t == 0) rowptr[NN] = carry;
}

__global__ __launch_bounds__(256) void k_scatter(const int* __restrict__ src,
                                                 const int* __restrict__ dst,
                                                 const int* __restrict__ eid,
                                                 int* cursor, int2* einfo) {
    int e = blockIdx.x * 256 + threadIdx.x;
    if (e >= NE) return;
    int slot = atomicAdd(&cursor[dst[e]], 1);
    einfo[slot] = make_int2(src[e] | (eid[e] << 20), e);
}

// ---------------- per-layer kernels ----------------

// vvec[r][k] = sum_c We[r][k][c] * aw[c]  (We = Wr rows 32:64)
__global__ __launch_bounds__(128) void k_prevec(const float* __restrict__ Wr,
                                                const float* __restrict__ attw,
                                                float* __restrict__ vvec) {
    int t = threadIdx.x;
    int r = t >> 5, k = t & 31;
    const float* row = Wr + (size_t)r * 3072 + 1024 + k * 32;
    float s = 0.f;
#pragma unroll
    for (int c = 0; c < 32; c++) s += row[c] * attw[32 + c];
    vvec[t] = s;
}

// One thread per node: featn, zF[r][n], Pd[r][n][:], znrd[r][n], loopb[n][:]
__global__ __launch_bounds__(256) void k_nodeproj(const float* __restrict__ feat,
                                                  const float* __restrict__ nfeat,
                                                  const float* __restrict__ Wr,
                                                  const float* __restrict__ attw,
                                                  const float* __restrict__ lw,
                                                  const int* __restrict__ degout,
                                                  float* __restrict__ featn,
                                                  float* __restrict__ zF,
                                                  float* __restrict__ Pd,
                                                  float* __restrict__ znrd,
                                                  float* __restrict__ loopb) {
    int n = blockIdx.x * 256 + threadIdx.x;
    if (n >= NN) return;
    int dg = degout[n];
    float sc0 = rsqrtf((float)(dg > 1 ? dg : 1));
    const float* fin = feat + (size_t)n * 32;
    const float* nin = nfeat + (size_t)n * 32;
    float fv[32];
    float acc[32];

    // featn = feat * deg_out^-1/2 (store + keep in regs)
#pragma unroll
    for (int k = 0; k < 32; k += 4) {
        float4 f4 = *(const float4*)&fin[k];
        fv[k] = f4.x * sc0; fv[k + 1] = f4.y * sc0; fv[k + 2] = f4.z * sc0; fv[k + 3] = f4.w * sc0;
    }
    float* fo = featn + (size_t)n * 32;
#pragma unroll
    for (int k = 0; k < 32; k += 4)
        *(float4*)&fo[k] = make_float4(fv[k], fv[k + 1], fv[k + 2], fv[k + 3]);

    // zn = nfeat . attw[0:32]
    float z0 = 0.f;
    for (int k = 0; k < 32; k++) z0 += nin[k] * attw[k];

    for (int r = 0; r < 4; r++) {
        const float* W = Wr + (size_t)r * 96 * 32;  // rows 0:32 (feat part)
#pragma unroll
        for (int i = 0; i < 32; i++) acc[i] = 0.f;
        for (int k4 = 0; k4 < 32; k4 += 4) {
            const float* Wk = W + k4 * 32;
#pragma unroll
            for (int i = 0; i < 32; i++) acc[i] += fv[k4] * Wk[i];
#pragma unroll
            for (int i = 0; i < 32; i++) acc[i] += fv[k4 + 1] * Wk[32 + i];
#pragma unroll
            for (int i = 0; i < 32; i++) acc[i] += fv[k4 + 2] * Wk[64 + i];
#pragma unroll
            for (int i = 0; i < 32; i++) acc[i] += fv[k4 + 3] * Wk[96 + i];
        }
        float zf = 0.f;
        for (int i = 0; i < 32; i++) zf += acc[i] * attw[32 + i];
        zF[r * NN + n] = zf;

        const float* W2 = W + 64 * 32;              // rows 64:96 (dst part)
#pragma unroll
        for (int i = 0; i < 32; i++) acc[i] = 0.f;
        for (int k4 = 0; k4 < 32; k4 += 4) {
            float4 f4 = *(const float4*)&nin[k4];
            const float* Wk = W2 + k4 * 32;
#pragma unroll
            for (int i = 0; i < 32; i++) acc[i] += f4.x * Wk[i];
#pragma unroll
            for (int i = 0; i < 32; i++) acc[i] += f4.y * Wk[32 + i];
#pragma unroll
            for (int i = 0; i < 32; i++) acc[i] += f4.z * Wk[64 + i];
#pragma unroll
            for (int i = 0; i < 32; i++) acc[i] += f4.w * Wk[96 + i];
        }
        float* qo = Pd + ((size_t)r * NN + n) * 32;
#pragma unroll
        for (int i = 0; i < 32; i += 4)
            *(float4*)&qo[i] = make_float4(acc[i], acc[i + 1], acc[i + 2], acc[i + 3]);
        float zd = 0.f;
        for (int i = 0; i < 32; i++) zd += acc[i] * attw[32 + i];
        znrd[r * NN + n] = z0 + zd;
    }

    // loopb = nfeat @ loop_w
#pragma unroll
    for (int i = 0; i < 32; i++) acc[i] = 0.f;
    for (int k4 = 0; k4 < 32; k4 += 4) {
        float4 f4 = *(const float4*)&nin[k4];
        const float* Wk = lw + k4 * 32;
#pragma unroll
        for (int i = 0; i < 32; i++) acc[i] += f4.x * Wk[i];
#pragma unroll
        for (int i = 0; i < 32; i++) acc[i] += f4.y * Wk[32 + i];
#pragma unroll
        for (int i = 0; i < 32; i++) acc[i] += f4.z * Wk[64 + i];
#pragma unroll
        for (int i = 0; i < 32; i++) acc[i] += f4.w * Wk[96 + i];
    }
    float* lo = loopb + (size_t)n * 32;
#pragma unroll
    for (int i = 0; i < 32; i += 4)
        *(float4*)&lo[i] = make_float4(acc[i], acc[i + 1], acc[i + 2], acc[i + 3]);
}

// Fused edge+aggregate: 32-lane half-wave per dst node, lane = column.
// Edge loop: only scalars + raw-row accumulation (VMEM+VALU); per-node
// epilogue does the 8 32x32 GEMVs via LDS weights + shfl broadcasts.
__global__ __launch_bounds__(512) void k_fagg(const int* __restrict__ rowptr,
                                              const int2* __restrict__ einfo,
                                              const float* __restrict__ efeat,
                                              const float* __restrict__ Wr,
                                              const float* __restrict__ featn,
                                              const float* __restrict__ zF,
                                              const float* __restrict__ znrd,
                                              const float* __restrict__ Pd,
                                              const float* __restrict__ vvec,
                                              const float* __restrict__ loopb,
                                              const float* __restrict__ hbias,
                                              float* __restrict__ hpre) {
    __shared__ float sWf[4096];  // Wf[r][k][c] = Wr[r][k][c]      (rows 0:32)
    __shared__ float sWe[4096];  // We[r][k][c] = Wr[r][32+k][c]   (rows 32:64)
    __shared__ float sV[128];
    int tid = threadIdx.x;
    for (int i = tid * 4; i < 4096; i += 2048) {
        int r = i >> 10, q = i & 1023;
        *(float4*)&sWf[i] = *(const float4*)&Wr[r * 3072 + q];
        *(float4*)&sWe[i] = *(const float4*)&Wr[r * 3072 + 1024 + q];
    }
    if (tid < 128) sV[tid] = vvec[tid];
    __syncthreads();

    int c = tid & 31;
    int n = blockIdx.x * 16 + (tid >> 5);   // grid covers NN exactly

    int rp0 = rowptr[n];
    int deg = rowptr[n + 1] - rp0;
    float pdv0 = Pd[((size_t)0 * NN + n) * 32 + c];
    float pdv1 = Pd[((size_t)1 * NN + n) * 32 + c];
    float pdv2 = Pd[((size_t)2 * NN + n) * 32 + c];
    float pdv3 = Pd[((size_t)3 * NN + n) * 32 + c];
    float zr0 = znrd[0 * NN + n], zr1 = znrd[1 * NN + n];
    float zr2 = znrd[2 * NN + n], zr3 = znrd[3 * NN + n];
    float vv0 = sV[0 * 32 + c], vv1 = sV[1 * 32 + c];
    float vv2 = sV[2 * 32 + c], vv3 = sV[3 * 32 + c];

    float yf0 = 0.f, yf1 = 0.f, yf2 = 0.f, yf3 = 0.f;
    float ye0 = 0.f, ye1 = 0.f, ye2 = 0.f, ye3 = 0.f;
    float w0 = 0.f, w1 = 0.f, w2 = 0.f, w3 = 0.f, den = 0.f;

    // 2-stage pipeline over edges
    int s = 0, r = 0;
    float ef = 0.f, fn = 0.f, zfs = 0.f;
    if (deg > 0) {
        int2 me = einfo[rp0];
        s = me.x & 0xFFFFF; r = me.x >> 20;
        ef = efeat[(size_t)me.y * 32 + c];
        fn = featn[(size_t)s * 32 + c];
        zfs = zF[r * NN + s];
    }
    for (int t = 0; t < deg; t++) {
        int rC = r;
        float efC = ef, fnC = fn, zfC = zfs;
        if (t + 1 < deg) {
            int2 me = einfo[rp0 + t + 1];
            s = me.x & 0xFFFFF; r = me.x >> 20;
            ef = efeat[(size_t)me.y * 32 + c];
            fn = featn[(size_t)s * 32 + c];
            zfs = zF[r * NN + s];
        }
        // ze = ef . v_r  (reduce across the 32-lane half)
        float vsel = (rC == 0) ? vv0 : (rC == 1) ? vv1 : (rC == 2) ? vv2 : vv3;
        float zq = efC * vsel;
        zq += __shfl_xor(zq, 16, 32);
        zq += __shfl_xor(zq, 8, 32);
        zq += __shfl_xor(zq, 4, 32);
        zq += __shfl_xor(zq, 2, 32);
        zq += __shfl_xor(zq, 1, 32);
        float zrs = (rC == 0) ? zr0 : (rC == 1) ? zr1 : (rC == 2) ? zr2 : zr3;
        float z = zrs + zfC + zq;
        z = z > 0.f ? z : 0.01f * z;         // leaky_relu
        float ez = __expf(z);                // softmax max-shift cancels
        float e0 = (rC == 0) ? ez : 0.f;
        float e1 = (rC == 1) ? ez : 0.f;
        float e2 = (rC == 2) ? ez : 0.f;
        float e3 = (rC == 3) ? ez : 0.f;
        yf0 += e0 * fnC; yf1 += e1 * fnC; yf2 += e2 * fnC; yf3 += e3 * fnC;
        ye0 += e0 * efC; ye1 += e1 * efC; ye2 += e2 * efC; ye3 += e3 * efC;
        w0 += e0; w1 += e1; w2 += e2; w3 += e3;
        den += ez;
    }

    // epilogue: num = sum_r w_r*Pd_r + sum_r yf_r@Wf_r + sum_r ye_r@We_r
    float num = w0 * pdv0 + w1 * pdv1 + w2 * pdv2 + w3 * pdv3;
#pragma unroll 8
    for (int k = 0; k < 32; k++) {
        float a0 = __shfl(yf0, k, 32), a1 = __shfl(yf1, k, 32);
        float a2 = __shfl(yf2, k, 32), a3 = __shfl(yf3, k, 32);
        float b0 = __shfl(ye0, k, 32), b1 = __shfl(ye1, k, 32);
        float b2 = __shfl(ye2, k, 32), b3 = __shfl(ye3, k, 32);
        int kc = k * 32 + c;
        num += a0 * sWf[kc] + a1 * sWf[1024 + kc] + a2 * sWf[2048 + kc] + a3 * sWf[3072 + kc];
        num += b0 * sWe[kc] + b1 * sWe[1024 + kc] + b2 * sWe[2048 + kc] + b3 * sWe[3072 + kc];
    }
    float h = (deg > 0) ? num / den : 0.f;
    h += loopb[(size_t)n * 32 + c];
    h *= rsqrtf((float)(deg > 1 ? deg : 1));
    h += hbias[c];
    hpre[(size_t)n * 32 + c] = h;
}

// One thread per node: AMRM + relu -> layer output
__global__ __launch_bounds__(256) void k_amrm(const float* __restrict__ hpre,
                                              const float* __restrict__ aW,
                                              const float* __restrict__ ab,
                                              const float* __restrict__ aa,
                                              float* __restrict__ out) {
    int n = blockIdx.x * 256 + threadIdx.x;
    if (n >= NN) return;
    const float* hp = hpre + (size_t)n * 32;

    float s[3];
#pragma unroll
    for (int l = 0; l < 3; l++) {
        float acc[32];
#pragma unroll
        for (int o = 0; o < 32; o++) acc[o] = ab[l * 32 + o];
        for (int h4 = 0; h4 < 32; h4 += 4) {
            float4 hv = *(const float4*)&hp[h4];
            const float* Wk = aW + ((size_t)l * 32 + h4) * 32;
#pragma unroll
            for (int o = 0; o < 32; o++) acc[o] += hv.x * Wk[o];
#pragma unroll
            for (int o = 0; o < 32; o++) acc[o] += hv.y * Wk[32 + o];
#pragma unroll
            for (int o = 0; o < 32; o++) acc[o] += hv.z * Wk[64 + o];
#pragma unroll
            for (int o = 0; o < 32; o++) acc[o] += hv.w * Wk[96 + o];
        }
        float sl = 0.f;
#pragma unroll
        for (int o = 0; o < 32; o++) {
            float lv = acc[o] > 0.f ? acc[o] : 0.f;
            sl += lv * aa[o];
        }
        s[l] = sl;
    }
    float mx = fmaxf(s[0], fmaxf(s[1], s[2]));
    float e0 = __expf(s[0] - mx), e1 = __expf(s[1] - mx), e2 = __expf(s[2] - mx);
    float inv = 1.f / (e0 + e1 + e2);
    float scl[3] = {e0 * inv, e1 * inv, e2 * inv};

    float outv[32];
#pragma unroll
    for (int o = 0; o < 32; o++) outv[o] = 0.f;
#pragma unroll
    for (int l = 0; l < 3; l++) {
        float acc[32];
#pragma unroll
        for (int o = 0; o < 32; o++) acc[o] = ab[l * 32 + o];
        for (int h4 = 0; h4 < 32; h4 += 4) {
            float4 hv = *(const float4*)&hp[h4];
            const float* Wk = aW + ((size_t)l * 32 + h4) * 32;
#pragma unroll
            for (int o = 0; o < 32; o++) acc[o] += hv.x * Wk[o];
#pragma unroll
            for (int o = 0; o < 32; o++) acc[o] += hv.y * Wk[32 + o];
#pragma unroll
            for (int o = 0; o < 32; o++) acc[o] += hv.z * Wk[64 + o];
#pragma unroll
            for (int o = 0; o < 32; o++) acc[o] += hv.w * Wk[96 + o];
        }
#pragma unroll
        for (int o = 0; o < 32; o++) {
            float lv = acc[o] > 0.f ? acc[o] : 0.f;
            outv[o] += scl[l] * lv;
        }
    }
    float* op = out + (size_t)n * 32;
#pragma unroll
    for (int o = 0; o < 32; o += 4) {
        float4 v = make_float4(fmaxf(outv[o], 0.f), fmaxf(outv[o + 1], 0.f),
                               fmaxf(outv[o + 2], 0.f), fmaxf(outv[o + 3], 0.f));
        *(float4*)&op[o] = v;
    }
}

// ---------------- host ----------------

static void launch_layer(const float* feat, const float* nf, const float* efeat,
                         const float* Wr, const float* attw, const float* lw,
                         const float* hb, const float* aW, const float* ab,
                         const float* aa, float* wsf, int* wsi, float* out,
                         hipStream_t stream) {
    k_prevec<<<1, 128, 0, stream>>>(Wr, attw, wsf + O_VV);
    k_nodeproj<<<196, 256, 0, stream>>>(feat, nf, Wr, attw, lw, wsi + O_DEGOUT,
                                        wsf + O_FEATN, wsf + O_ZF, wsf + O_PD,
                                        wsf + O_ZNRD, wsf + O_LOOPB);
    k_fagg<<<NN / 16, 512, 0, stream>>>(wsi + O_ROWPTR, (const int2*)(wsi + O_EINFO),
                                        efeat, Wr, wsf + O_FEATN, wsf + O_ZF,
                                        wsf + O_ZNRD, wsf + O_PD, wsf + O_VV,
                                        wsf + O_LOOPB, hb, wsf + O_HPRE);
    k_amrm<<<196, 256, 0, stream>>>(wsf + O_HPRE, aW, ab, aa, out);
}

extern "C" void kernel_launch(void* const* d_in, const int* in_sizes, int n_in,
                              void* d_out, int out_size, void* d_ws, size_t ws_size,
                              hipStream_t stream) {
    const float* x     = (const float*)d_in[0];
    const float* nfeat = (const float*)d_in[1];
    const float* efeat = (const float*)d_in[2];
    const int*   src   = (const int*)d_in[3];
    const int*   dst   = (const int*)d_in[4];
    const int*   eid   = (const int*)d_in[5];
    const float* Wr1   = (const float*)d_in[6];
    const float* attw1 = (const float*)d_in[7];
    const float* lw1   = (const float*)d_in[8];
    const float* hb1   = (const float*)d_in[9];
    const float* aW1   = (const float*)d_in[10];
    const float* ab1   = (const float*)d_in[11];
    const float* aa1   = (const float*)d_in[12];
    const float* Wr2   = (const float*)d_in[13];
    const float* attw2 = (const float*)d_in[14];
    const float* lw2   = (const float*)d_in[15];
    const float* hb2   = (const float*)d_in[16];
    const float* aW2   = (const float*)d_in[17];
    const float* ab2   = (const float*)d_in[18];
    const float* aa2   = (const float*)d_in[19];

    float* wsf = (float*)d_ws;
    int*   wsi = (int*)d_ws;
    float* out = (float*)d_out;

    // zero degree counters (degin + degout)
    hipMemsetAsync(d_ws, 0, (size_t)O_ROWPTR * 4, stream);

    k_deg<<<NE / 256, 256, 0, stream>>>(src, dst, wsi + O_DEGIN, wsi + O_DEGOUT);
    k_scan<<<1, 1024, 0, stream>>>(wsi + O_DEGIN, wsi + O_ROWPTR, wsi + O_CURSOR);
    k_scatter<<<NE / 256, 256, 0, stream>>>(src, dst, eid, wsi + O_CURSOR,
                                            (int2*)(wsi + O_EINFO));

    // layer 1: feat = x -> h1 (ws)
    launch_layer(x, nfeat, efeat, Wr1, attw1, lw1, hb1, aW1, ab1, aa1,
                 wsf, wsi, wsf + O_H1, stream);
    // layer 2: feat = h1 -> d_out
    launch_layer(wsf + O_H1, nfeat, efeat, Wr2, attw2, lw2, hb2, aW2, ab2, aa2,
                 wsf, wsi, out, stream);
}